// Round 1
// baseline (400.811 us; speedup 1.0000x reference)
//
#include <hip/hip_runtime.h>
#include <math.h>

#define NPTS 512
#define HIDDEN 128
#define RELD 64

// One thread per (b,i,j) pair. 64 fp32 accumulators in VGPRs.
// All weight accesses are wave-uniform -> compiler emits scalar loads
// (SGPR operands for the FMAs), no LDS needed.
__global__ __launch_bounds__(256) void relgeom_kernel(
    const float* __restrict__ pos, const float* __restrict__ color,
    const float* __restrict__ size, const float* __restrict__ W1,
    const float* __restrict__ b1, const float* __restrict__ W2,
    const float* __restrict__ b2, float* __restrict__ out)
{
    const int t = blockIdx.x * blockDim.x + threadIdx.x;   // pair id
    const int j  = t & (NPTS - 1);
    const int bi = t >> 9;
    const int i  = bi & (NPTS - 1);
    const int b  = bi >> 9;

    const int pi = b * NPTS + i;
    const int pj = b * NPTS + j;

    // --- build 7 geometry features ---
    const float pix = pos[pi * 2 + 0], piy = pos[pi * 2 + 1];
    const float pjx = pos[pj * 2 + 0], pjy = pos[pj * 2 + 1];
    const float dx = pix - pjx;
    const float dy = piy - pjy;
    const float dist = sqrtf(fmaf(dx, dx, fmaf(dy, dy, 1e-6f)));

    float g[7];
    g[0] = dist;
    g[1] = dx;
    g[2] = dy;
    g[3] = color[pi * 3 + 0] - color[pj * 3 + 0];
    g[4] = color[pi * 3 + 1] - color[pj * 3 + 1];
    g[5] = color[pi * 3 + 2] - color[pj * 3 + 2];
    g[6] = size[pi] - size[pj];

    float acc[RELD];
#pragma unroll
    for (int r = 0; r < RELD; ++r) acc[r] = b2[r];

    for (int k = 0; k < HIDDEN; ++k) {
        float h = b1[k];
#pragma unroll
        for (int c = 0; c < 7; ++c) h = fmaf(g[c], W1[c * HIDDEN + k], h);
        // exact GELU: x * 0.5 * (1 + erf(x/sqrt(2)))
        h = 0.5f * h * (1.0f + erff(h * 0.70710678118654752f));
        const float* __restrict__ w2row = W2 + k * RELD;
#pragma unroll
        for (int r = 0; r < RELD; ++r) acc[r] = fmaf(h, w2row[r], acc[r]);
    }

    float* __restrict__ o = out + (size_t)t * RELD;
#pragma unroll
    for (int r = 0; r < RELD; ++r) o[r] = acc[r];
}

extern "C" void kernel_launch(void* const* d_in, const int* in_sizes, int n_in,
                              void* d_out, int out_size, void* d_ws, size_t ws_size,
                              hipStream_t stream) {
    const float* pos   = (const float*)d_in[0];
    const float* color = (const float*)d_in[1];
    const float* size  = (const float*)d_in[2];
    const float* W1    = (const float*)d_in[3];
    const float* b1    = (const float*)d_in[4];
    const float* W2    = (const float*)d_in[5];
    const float* b2    = (const float*)d_in[6];
    float* out = (float*)d_out;

    const int B = in_sizes[0] / (NPTS * 2);
    const long long pairs = (long long)B * NPTS * NPTS;
    const int block = 256;
    const int grid = (int)((pairs + block - 1) / block);

    relgeom_kernel<<<grid, block, 0, stream>>>(pos, color, size, W1, b1, W2, b2, out);
}

// Round 2
// 85.931 us; speedup vs baseline: 4.6643x; 4.6643x over previous
//
#include <hip/hip_runtime.h>
#include <math.h>

#define NPTS 512
#define HID 128
#define RELD 64

typedef __attribute__((ext_vector_type(8))) short short8;
typedef __attribute__((ext_vector_type(4))) float f32x4;
typedef __attribute__((ext_vector_type(4))) int i32x4;

// Per wave: 64 consecutive pairs (same b,i; j = j0..j0+63). Lane = pair.
// Stage 1: h = GELU(geom @ W1 + b1) computed with wave-uniform W1 (scalar loads).
// LDS bounce (per-wave private, XOR-swizzled) converts lane-major h into
// mfma_f32_16x16x32_bf16 A-fragments. Stage 2: 4x4 C-tiles (64 pairs x 64 out).
__global__ __launch_bounds__(256) void relgeom_mfma(
    const float* __restrict__ pos, const float* __restrict__ color,
    const float* __restrict__ size, const float* __restrict__ W1,
    const float* __restrict__ b1, const float* __restrict__ W2,
    const float* __restrict__ b2, float* __restrict__ out)
{
  __shared__ __align__(16) char lds[16384 + 4 * 4096];  // w2t 16KB + 4 waves * 4KB
  const int tid = threadIdx.x;
  const int lane = tid & 63;
  const int wid = tid >> 6;
  const int l15 = lane & 15, lq = lane >> 4, l3 = lane & 3;

  // ---- stage W2 (fp32 [128][64]) -> LDS bf16 transposed [64 r][128 k], swizzled ----
#pragma unroll
  for (int n = 0; n < 32; ++n) {
    const int m = tid + 256 * n;          // 8192 elements
    const int k = m >> 6, r = m & 63;     // W2[k][r]
    const __bf16 wb = (__bf16)W2[m];
    *(__bf16*)(lds + r * 256 + (((k >> 3) ^ (r & 7)) << 4) + (k & 7) * 2) = wb;
  }
  __syncthreads();

  // ---- geometry features for my pair ----
  const int pbase = (blockIdx.x * 4 + wid) * 64;
  const int t = pbase + lane;
  const int j = t & (NPTS - 1);
  const int bi = t >> 9;
  const int i = bi & (NPTS - 1);
  const int b = bi >> 9;
  const int pi = b * NPTS + i, pj = b * NPTS + j;

  const float dx = pos[pi * 2 + 0] - pos[pj * 2 + 0];
  const float dy = pos[pi * 2 + 1] - pos[pj * 2 + 1];
  const float g0 = sqrtf(fmaf(dx, dx, fmaf(dy, dy, 1e-6f)));
  const float g3 = color[pi * 3 + 0] - color[pj * 3 + 0];
  const float g4 = color[pi * 3 + 1] - color[pj * 3 + 1];
  const float g5 = color[pi * 3 + 2] - color[pj * 3 + 2];
  const float g6 = size[pi] - size[pj];

  f32x4 acc[4][4];
#pragma unroll
  for (int nt = 0; nt < 4; ++nt) {
    const float bb = b2[nt * 16 + l15];   // C-layout: col = lane&15, same for all 4 regs
#pragma unroll
    for (int s = 0; s < 4; ++s) acc[s][nt] = (f32x4){bb, bb, bb, bb};
  }

  char* const hbase = lds + 16384 + wid * 4096;  // per-wave private: no barriers needed

  for (int ks = 0; ks < 4; ++ks) {
    union { short s[32]; i32x4 v[4]; } hb;
#pragma unroll
    for (int kk = 0; kk < 32; ++kk) {
      const int k = ks * 32 + kk;         // uniform -> W1/b1 via scalar loads
      float h = b1[k];
      h = fmaf(g0, W1[0 * HID + k], h);
      h = fmaf(dx, W1[1 * HID + k], h);
      h = fmaf(dy, W1[2 * HID + k], h);
      h = fmaf(g3, W1[3 * HID + k], h);
      h = fmaf(g4, W1[4 * HID + k], h);
      h = fmaf(g5, W1[5 * HID + k], h);
      h = fmaf(g6, W1[6 * HID + k], h);
      // gelu_tanh(h) = h * sigmoid(2*0.79788456*(h + 0.044715 h^3)); exp2-folded
      const float h2 = h * h;
      const float wq = fmaf(h2, -0.1029534f, -2.3022077f);
      const float ex = __builtin_amdgcn_exp2f(h * wq);
      const float gel = h * __builtin_amdgcn_rcpf(1.0f + ex);
      const __bf16 hbf = (__bf16)gel;
      hb.s[kk] = __builtin_bit_cast(short, hbf);
    }
    // write my row (64B), granule-XOR-swizzled within the row
#pragma unroll
    for (int d = 0; d < 4; ++d)
      *(i32x4*)(hbase + lane * 64 + ((d ^ l3) << 4)) = hb.v[d];

    // B fragments for this k-chunk: B[k][n], n = lane&15, k = 8*(lane>>4)+e
    short8 bfr[4];
#pragma unroll
    for (int nt = 0; nt < 4; ++nt) {
      const int r = nt * 16 + l15;
      bfr[nt] = *(const short8*)(lds + r * 256 + (((ks * 4 + lq) ^ (r & 7)) << 4));
    }
    // A fragments (row = lane&15 within strip, k = 8*(lane>>4)+e) + MFMA
#pragma unroll
    for (int s = 0; s < 4; ++s) {
      const short8 af = *(const short8*)(hbase + (s * 16 + l15) * 64 + ((lq ^ l3) << 4));
#pragma unroll
      for (int nt = 0; nt < 4; ++nt)
        acc[s][nt] = __builtin_amdgcn_mfma_f32_16x16x32_bf16(af, bfr[nt], acc[s][nt], 0, 0, 0);
    }
  }

  // epilogue: D row = 4*(lane>>4)+reg, col = lane&15
  float* const op = out + (size_t)pbase * RELD;
#pragma unroll
  for (int s = 0; s < 4; ++s)
#pragma unroll
    for (int nt = 0; nt < 4; ++nt)
#pragma unroll
      for (int ri = 0; ri < 4; ++ri)
        op[(s * 16 + lq * 4 + ri) * RELD + nt * 16 + l15] = acc[s][nt][ri];
}

extern "C" void kernel_launch(void* const* d_in, const int* in_sizes, int n_in,
                              void* d_out, int out_size, void* d_ws, size_t ws_size,
                              hipStream_t stream) {
  const float* pos   = (const float*)d_in[0];
  const float* color = (const float*)d_in[1];
  const float* size  = (const float*)d_in[2];
  const float* W1    = (const float*)d_in[3];
  const float* b1    = (const float*)d_in[4];
  const float* W2    = (const float*)d_in[5];
  const float* b2    = (const float*)d_in[6];
  float* out = (float*)d_out;

  const int B = in_sizes[0] / (NPTS * 2);
  const long long pairs = (long long)B * NPTS * NPTS;
  const int grid = (int)(pairs / 256);   // 4 waves/block, 64 pairs/wave

  relgeom_mfma<<<grid, 256, 0, stream>>>(pos, color, size, W1, b1, W2, b2, out);
}